// Round 6
// baseline (470.250 us; speedup 1.0000x reference)
//
#include <hip/hip_runtime.h>

// LSTM: B=8192, T=512, H=32. ONE WAVE (64 threads) per 16 batches; 512 blocks.
// Fully register-resident recurrence: transposed MFMA D = W'*h with tile t8's
// row m = (gate m&3, unit 8*(m>>2)+t8) and IDENTITY k-permutation. Then:
//   - C/D layout: lane (c=lane&15, q=lane>>4), tile t8, reg r
//       = gate r of cell (unit 8q+t8, batch c)  -> lane owns 8 whole cells
//   - B-fragment lane (c,q) must supply = h[units 8q..8q+7][batch c]
//       = exactly the lane's own 8 cells -> next operand built in-register.
// => NO LDS, NO barriers in the 512-step loop. Only true dep h(t)->MFMA(t+1).
// hi/lo bf16 split (3 chained MFMAs) for fp32-grade matvec; x-term + bias in
// the MFMA C-initializer; gates pre-scaled by -log2e (i,f,o) / +2log2e (g);
// cell = 5 exp2 + 2 rcp via fused-denominator identities (exact algebra).

#define TT 512
#define HH 32
#define L2E 1.44269504088896340736f

typedef short bf16x8 __attribute__((ext_vector_type(8)));
typedef float f32x4 __attribute__((ext_vector_type(4)));

__device__ __forceinline__ short f2bf(float f) {
    unsigned u = __float_as_uint(f);
    u = (u + 0x7FFFu + ((u >> 16) & 1u)) >> 16;
    return (short)u;
}
__device__ __forceinline__ float bf2f(short s) {
    return __uint_as_float(((unsigned)(unsigned short)s) << 16);
}
__device__ __forceinline__ float fastrcp(float x) { return __builtin_amdgcn_rcpf(x); }
__device__ __forceinline__ float exp2f_(float x) { return __builtin_amdgcn_exp2f(x); }

__launch_bounds__(64, 1)
__global__ void lstm_kernel(const float* __restrict__ x,
                            const float* __restrict__ W_ih,
                            const float* __restrict__ W_hh,
                            const float* __restrict__ b_ih,
                            const float* __restrict__ b_hh,
                            const float* __restrict__ W_fc,
                            const float* __restrict__ b_fc,
                            float* __restrict__ out) {
    const int lane = threadIdx.x;
    const int c    = lane & 15;       // batch-in-group = MFMA n; also A m-row
    const int q    = lane >> 4;       // quad: k-block q*8.. ; unit-block 8q..
    const int base = blockIdx.x * 16;

    // ---- A-fragments (weights), 8 tiles, hi/lo bf16 split ----
    // Lane supplies A[m=c][k=q*8+j] of tile t8. Row c of tile t8 =
    // (gate c&3, unit 8*(c>>2)+t8); W_hh row = 32*gate + unit; k = unit index.
    const int gate = c & 3;
    const float asc = (gate == 2) ? (2.0f * L2E) : (-L2E);
    const int wbase = gate * 32 + 8 * (c >> 2);
    bf16x8 wah[8], wal[8];
    #pragma unroll
    for (int t8 = 0; t8 < 8; ++t8) {
        #pragma unroll
        for (int j = 0; j < 8; ++j) {
            const float wf = W_hh[(wbase + t8) * HH + q * 8 + j] * asc;
            const short hi = f2bf(wf);
            wah[t8][j] = hi;
            wal[t8][j] = f2bf(wf - bf2f(hi));
        }
    }

    // ---- per-cell x-weights / biases: cell t8 = (unit 8q+t8, batch c) ----
    float wihs[8][4], bcs[8][4];
    #pragma unroll
    for (int t8 = 0; t8 < 8; ++t8) {
        const int u = 8 * q + t8;
        #pragma unroll
        for (int r = 0; r < 4; ++r) {
            const float sc = (r == 2) ? (2.0f * L2E) : (-L2E);
            wihs[t8][r] = W_ih[32 * r + u] * sc;
            bcs[t8][r]  = (b_ih[32 * r + u] + b_hh[32 * r + u]) * sc;
        }
    }

    // ---- state ----
    float cs[8], hf[8];
    #pragma unroll
    for (int i = 0; i < 8; ++i) { cs[i] = 0.f; hf[i] = 0.f; }
    bf16x8 bh = {0, 0, 0, 0, 0, 0, 0, 0};   // h hi (B-fragment), h0 = 0
    bf16x8 bl = {0, 0, 0, 0, 0, 0, 0, 0};   // h lo

    // ---- x prefetch: double-buffered float4 (8-step lookahead) ----
    const float* __restrict__ xp = &x[(base + c) * TT];
    float4 xcur = *(const float4*)&xp[0];
    float4 xnxt = *(const float4*)&xp[4];

    for (int tb = 0; tb < TT; tb += 4) {
        const float xs[4] = {xcur.x, xcur.y, xcur.z, xcur.w};
        xcur = xnxt;
        int nidx = tb + 8; if (nidx > TT - 4) nidx = TT - 4;
        xnxt = *(const float4*)&xp[nidx];

        #pragma unroll
        for (int ts = 0; ts < 4; ++ts) {
            const float xc = xs[ts];

            // -- 8 independent 3-MFMA chains; C-init carries x-term + bias --
            f32x4 acc[8];
            #pragma unroll
            for (int t8 = 0; t8 < 8; ++t8) {
                f32x4 a;
                #pragma unroll
                for (int r = 0; r < 4; ++r) a[r] = wihs[t8][r] * xc + bcs[t8][r];
                a = __builtin_amdgcn_mfma_f32_16x16x32_bf16(wah[t8], bh, a, 0, 0, 0);
                a = __builtin_amdgcn_mfma_f32_16x16x32_bf16(wah[t8], bl, a, 0, 0, 0);
                a = __builtin_amdgcn_mfma_f32_16x16x32_bf16(wal[t8], bh, a, 0, 0, 0);
                acc[t8] = a;
            }

            // -- 8 cell updates; write next B-fragment in-register --
            bf16x8 nbh, nbl;
            #pragma unroll
            for (int t8 = 0; t8 < 8; ++t8) {
                const float Ei = exp2f_(acc[t8][0]);   // 2^(-pi*l2e)
                const float Ef = exp2f_(acc[t8][1]);   // 2^(-pf*l2e)
                const float G  = exp2f_(acc[t8][2]);   // 2^(2*pg*l2e)
                const float Eo = exp2f_(acc[t8][3]);   // 2^(-po*l2e)
                // cn = cs/(1+Ef) + (G-1)/((1+Ei)(G+1))  via one rcp
                const float aig = (1.f + Ei) * (G + 1.f);
                const float af  = 1.f + Ef;
                const float num = cs[t8] * aig + (G - 1.f) * af;
                const float cn  = num * fastrcp(af * aig);
                cs[t8] = cn;
                float yc = cn * (2.0f * L2E);
                yc = fminf(60.f, fmaxf(-60.f, yc));
                const float C = exp2f_(yc);
                const float h = (C - 1.f) * fastrcp((C + 1.f) * (1.f + Eo));
                hf[t8] = h;
                const short h16 = f2bf(h);
                nbh[t8] = h16;
                nbl[t8] = f2bf(h - bf2f(h16));
            }
            bh = nbh;
            bl = nbl;
        }
    }

    // ---- head: out[b] = h_T @ W_fc^T + b_fc; reduce over q (units) ----
    float partial = 0.f;
    #pragma unroll
    for (int t8 = 0; t8 < 8; ++t8) partial += hf[t8] * W_fc[8 * q + t8];
    partial += __shfl_xor(partial, 16);
    partial += __shfl_xor(partial, 32);
    if (q == 0) out[base + c] = partial + b_fc[0];
}

extern "C" void kernel_launch(void* const* d_in, const int* in_sizes, int n_in,
                              void* d_out, int out_size, void* d_ws, size_t ws_size,
                              hipStream_t stream) {
    const float* x    = (const float*)d_in[0];
    const float* W_ih = (const float*)d_in[1];
    const float* W_hh = (const float*)d_in[2];
    const float* b_ih = (const float*)d_in[3];
    const float* b_hh = (const float*)d_in[4];
    const float* W_fc = (const float*)d_in[5];
    const float* b_fc = (const float*)d_in[6];
    float* out = (float*)d_out;

    const int B = 8192;
    lstm_kernel<<<B / 16, 64, 0, stream>>>(x, W_ih, W_hh, b_ih, b_hh,
                                           W_fc, b_fc, out);
}

// Round 7
// 282.866 us; speedup vs baseline: 1.6624x; 1.6624x over previous
//
#include <hip/hip_runtime.h>
#include <hip/hip_bf16.h>

// LSTM: B=8192, T=512, H=32. Block = 256 threads (4 waves) per 16-batch group;
// 512 blocks -> 2048 waves -> 8 waves/CU (2/SIMD, from 2 different blocks).
// Transposed MFMA D = W'*h (identity k-perm): tile t8 row m = (gate m&3,
// unit 8*(m>>2)+t8); C/D layout gives lane (c,q) reg r = gate r of cell
// (unit 8q+t8, batch c). Wave w owns tiles {2w, 2w+1} -> 2 cells/lane, and
// its two cells are ADJACENT unit-slots (8q+2w, 8q+2w+1) -> h exchange is one
// b32 write (hi) + one b32 write (lo) per lane into ping-pong planes laid out
// [qblk][batch][j] so the next step's B-fragment is a direct b128 read.
// One barrier/step. hi/lo bf16 split (3 MFMAs/tile) = fp32-grade matvec; bias
// rides the MFMA C-input; x-term added post-MFMA in fp32. Gates pre-scaled by
// -log2e (i,f,o) / +2log2e (g); cell = 5 exp2 + 2 rcp (exact identities).

#define TT 512
#define HH 32
#define L2E 1.44269504088896340736f

typedef short bf16x8 __attribute__((ext_vector_type(8)));
typedef float f32x4 __attribute__((ext_vector_type(4)));

__device__ __forceinline__ short f2bf(float f) {
    unsigned u = __float_as_uint(f);
    u = (u + 0x7FFFu + ((u >> 16) & 1u)) >> 16;
    return (short)u;
}
__device__ __forceinline__ float bf2f(short s) {
    return __uint_as_float(((unsigned)(unsigned short)s) << 16);
}
__device__ __forceinline__ float fastrcp(float x) { return __builtin_amdgcn_rcpf(x); }
__device__ __forceinline__ float exp2f_(float x) { return __builtin_amdgcn_exp2f(x); }

#define XROW 132   // x tile row stride (floats): bank (4c+t) mod 32 -> 2-way

__launch_bounds__(256, 2)
__global__ void lstm_kernel(const float* __restrict__ x,
                            const float* __restrict__ W_ih,
                            const float* __restrict__ W_hh,
                            const float* __restrict__ b_ih,
                            const float* __restrict__ b_hh,
                            const float* __restrict__ W_fc,
                            const float* __restrict__ b_fc,
                            float* __restrict__ out) {
    // h planes: [parity][qblk(4)][batch(16)][j(8)] shorts = 512 per parity
    __shared__ short hhp[2][512];
    __shared__ short hlp[2][512];
    __shared__ float xbuf[16 * XROW];

    const int tid  = threadIdx.x;
    const int lane = tid & 63;
    const int w    = tid >> 6;        // wave id 0..3: owns tiles 2w, 2w+1
    const int c    = lane & 15;       // batch (MFMA n); also A m-row
    const int q    = lane >> 4;       // quad: k-block 8q; unit-block 8q
    const int base = blockIdx.x * 16;

    // ---- A-fragments (weights) for tiles 2w+tt, hi/lo bf16 split ----
    // Lane supplies A[m=c][k=8q+j]; row c of tile t8 = (gate c&3, unit 8*(c>>2)+t8)
    const int gate = c & 3;
    const float asc = (gate == 2) ? (2.0f * L2E) : (-L2E);
    const int wrow0 = gate * 32 + 8 * (c >> 2);
    bf16x8 wah[2], wal[2];
    #pragma unroll
    for (int tt = 0; tt < 2; ++tt) {
        const int t8 = 2 * w + tt;
        #pragma unroll
        for (int j = 0; j < 8; ++j) {
            const float wf = W_hh[(wrow0 + t8) * HH + 8 * q + j] * asc;
            const short hi = f2bf(wf);
            wah[tt][j] = hi;
            wal[tt][j] = f2bf(wf - bf2f(hi));
        }
    }

    // ---- per-cell consts: cell tt = (unit 8q + 2w + tt, batch c) ----
    float wihs[2][4];
    f32x4 bcs[2];
    #pragma unroll
    for (int tt = 0; tt < 2; ++tt) {
        const int u = 8 * q + 2 * w + tt;
        #pragma unroll
        for (int r = 0; r < 4; ++r) {
            const float sc = (r == 2) ? (2.0f * L2E) : (-L2E);
            wihs[tt][r] = W_ih[32 * r + u] * sc;
            bcs[tt][r]  = (b_ih[32 * r + u] + b_hh[32 * r + u]) * sc;
        }
    }

    // ---- init parity-0 h planes to zero (h0 = 0) ----
    #pragma unroll
    for (int i = tid; i < 512; i += 256) { hhp[0][i] = 0; hlp[0][i] = 0; }

    float cs[2] = {0.f, 0.f};

    // x staging: 16 rows x 128 floats, 512 float4 over 256 threads (2 each)
    const int xrow = tid >> 4;
    const int xj4  = (tid & 15) * 4;

    // B-frag read offset (shorts) and h write offset (shorts)
    const int rdo = q * 128 + c * 8;
    const int wro = q * 128 + c * 8 + 2 * w;

    #define STEP(t, RP, WP)                                                   \
    {                                                                         \
        const bf16x8 bh = *(const bf16x8*)&hhp[RP][rdo];                      \
        const bf16x8 bl = *(const bf16x8*)&hlp[RP][rdo];                      \
        const float xc = xbuf[c * XROW + ((t) & 127)];                        \
        f32x4 acc[2];                                                         \
        _Pragma("unroll")                                                     \
        for (int tt = 0; tt < 2; ++tt) {                                      \
            f32x4 a = bcs[tt];                                                \
            a = __builtin_amdgcn_mfma_f32_16x16x32_bf16(wah[tt], bh, a, 0,0,0);\
            a = __builtin_amdgcn_mfma_f32_16x16x32_bf16(wah[tt], bl, a, 0,0,0);\
            a = __builtin_amdgcn_mfma_f32_16x16x32_bf16(wal[tt], bh, a, 0,0,0);\
            acc[tt] = a;                                                      \
        }                                                                     \
        float hv[2];                                                          \
        _Pragma("unroll")                                                     \
        for (int tt = 0; tt < 2; ++tt) {                                      \
            const float Ei = exp2f_(acc[tt][0] + wihs[tt][0] * xc);           \
            const float Ef = exp2f_(acc[tt][1] + wihs[tt][1] * xc);           \
            const float G  = exp2f_(acc[tt][2] + wihs[tt][2] * xc);           \
            const float Eo = exp2f_(acc[tt][3] + wihs[tt][3] * xc);           \
            const float aig = (1.f + Ei) * (G + 1.f);                         \
            const float af  = 1.f + Ef;                                       \
            const float num = cs[tt] * aig + (G - 1.f) * af;                  \
            const float cn  = num * fastrcp(af * aig);                        \
            cs[tt] = cn;                                                      \
            float yc = cn * (2.0f * L2E);                                     \
            yc = fminf(60.f, fmaxf(-60.f, yc));                               \
            const float C = exp2f_(yc);                                       \
            hv[tt] = (C - 1.f) * fastrcp((C + 1.f) * (1.f + Eo));             \
        }                                                                     \
        union { __hip_bfloat162 b; int i; } ph, pl;                           \
        ph.b = __float22bfloat162_rn(make_float2(hv[0], hv[1]));              \
        const float h0h = bf2f((short)(ph.i & 0xFFFF));                       \
        const float h1h = bf2f((short)((unsigned)ph.i >> 16));                \
        pl.b = __float22bfloat162_rn(make_float2(hv[0] - h0h, hv[1] - h1h));  \
        *(int*)&hhp[WP][wro] = ph.i;                                          \
        *(int*)&hlp[WP][wro] = pl.i;                                          \
        __syncthreads();                                                      \
    }

    for (int t = 0; t < TT; t += 2) {
        if ((t & 127) == 0) {
            #pragma unroll
            for (int s = 0; s < 2; ++s) {
                const float4 v = *(const float4*)&x[(base + xrow) * TT + t + xj4 + 64 * s];
                *(float4*)&xbuf[xrow * XROW + xj4 + 64 * s] = v;
            }
            __syncthreads();
        }
        STEP(t,     0, 1);   // read parity 0 (h(t)), write parity 1 (h(t+1))
        STEP(t + 1, 1, 0);   // read parity 1, write parity 0
    }
    // T even -> final h(512) is in parity-0 planes; loop ended with a barrier.

    // ---- head: out[b] = h_T @ W_fc^T + b_fc ----
    if (tid < 16) {
        float s = b_fc[0];
        #pragma unroll
        for (int u = 0; u < 32; ++u) {
            const int off = (u >> 3) * 128 + tid * 8 + (u & 7);
            s += (bf2f(hhp[0][off]) + bf2f(hlp[0][off])) * W_fc[u];
        }
        out[base + tid] = s;
    }
}

extern "C" void kernel_launch(void* const* d_in, const int* in_sizes, int n_in,
                              void* d_out, int out_size, void* d_ws, size_t ws_size,
                              hipStream_t stream) {
    const float* x    = (const float*)d_in[0];
    const float* W_ih = (const float*)d_in[1];
    const float* W_hh = (const float*)d_in[2];
    const float* b_ih = (const float*)d_in[3];
    const float* b_hh = (const float*)d_in[4];
    const float* W_fc = (const float*)d_in[5];
    const float* b_fc = (const float*)d_in[6];
    float* out = (float*)d_out;

    const int B = 8192;
    lstm_kernel<<<B / 16, 256, 0, stream>>>(x, W_ih, W_hh, b_ih, b_hh,
                                            W_fc, b_fc, out);
}